// Round 8
// baseline (51.441 us; speedup 1.0000x reference)
//
#include <hip/hip_runtime.h>

#define BSZ  8
#define LSEQ 2048
#define DM   256
#define NS   16
#define NC   64          // chunks along L
#define LC   (LSEQ/NC)   // 32 timesteps per chunk

// ---------------------------------------------------------------------------
// Kernel 1: per-(b,d,chunk) local scan, h0=0; emit carry c_j[16].
// carry layout: [b][chunk][n][d]  (d contiguous -> coalesced)
// Plain rolling loop (round-7 lesson: deep register staging is neutral;
// round-4 lesson: never cap VGPRs with launch_bounds here).
// ---------------------------------------------------------------------------
__global__ void k_local(
        const float* __restrict__ x,
        const float* __restrict__ A,
        const float* __restrict__ Bm,
        const float* __restrict__ delta,
        float* __restrict__ carry) {
    const int d     = threadIdx.x;
    const int chunk = blockIdx.x & (NC - 1);
    const int b     = blockIdx.x / NC;

    const float dt = 1.0f / (1.0f + expf(-delta[d]));
    float a[NS], bb[NS];
#pragma unroll
    for (int n = 0; n < NS; ++n) {
        a[n]  = expf(dt * A[d * NS + n]);
        bb[n] = dt * Bm[d * NS + n];
    }

    float h[NS];
#pragma unroll
    for (int n = 0; n < NS; ++n) h[n] = 0.0f;

    const float* xp = x + ((size_t)(b * LSEQ + chunk * LC)) * DM + d;
#pragma unroll 4
    for (int t = 0; t < LC; ++t) {
        const float xv = xp[(size_t)t * DM];
#pragma unroll
        for (int n = 0; n < NS; ++n) h[n] = fmaf(a[n], h[n], bb[n] * xv);
    }

    float* cp = carry + ((size_t)(b * NC + chunk) * NS) * DM + d;
#pragma unroll
    for (int n = 0; n < NS; ++n) cp[(size_t)n * DM] = h[n];
}

// ---------------------------------------------------------------------------
// Kernel 2: fused prefix + final scan.  Each (b,chunk=j) block REDUNDANTLY
// computes its entry state from the carries of chunks 0..j-1 via Horner:
//   h_entry = sum_{i<j} aL^{j-1-i} * c_i     (aL = exp(dt*A*LC))
// j*16 coalesced L2/L3 loads + a ~j-step dependent FMA chain per thread.
// Then the seeded scan: y_t = <h_t, C_d> + D_d * x_t.
// This deletes the pass-2 kernel + one launch gap from the critical path.
// ---------------------------------------------------------------------------
__global__ void k_final(
        const float* __restrict__ x,
        const float* __restrict__ A,
        const float* __restrict__ Bm,
        const float* __restrict__ Cm,
        const float* __restrict__ Dv,
        const float* __restrict__ delta,
        const float* __restrict__ carry,
        float* __restrict__ y) {
    const int d     = threadIdx.x;
    const int chunk = blockIdx.x & (NC - 1);
    const int b     = blockIdx.x / NC;

    const float dt = 1.0f / (1.0f + expf(-delta[d]));
    float a[NS], bb[NS], cc[NS], aL[NS];
#pragma unroll
    for (int n = 0; n < NS; ++n) {
        const float An = A[d * NS + n];
        a[n]  = expf(dt * An);
        aL[n] = expf(dt * An * (float)LC);
        bb[n] = dt * Bm[d * NS + n];
        cc[n] = Cm[d * NS + n];
    }
    const float Dd = Dv[d];

    // redundant chunk-prefix: Horner over carries of chunks 0..chunk-1
    float h[NS];
#pragma unroll
    for (int n = 0; n < NS; ++n) h[n] = 0.0f;
    {
        const float* cb = carry + ((size_t)b * NC * NS) * DM + d;
#pragma unroll 4
        for (int i = 0; i < chunk; ++i) {
            const float* ci = cb + (size_t)i * NS * DM;
#pragma unroll
            for (int n = 0; n < NS; ++n)
                h[n] = fmaf(aL[n], h[n], ci[(size_t)n * DM]);
        }
    }

    // seeded scan over this chunk
    const size_t base = ((size_t)(b * LSEQ + chunk * LC)) * DM + d;
    const float* xp = x + base;
    float*       yp = y + base;
#pragma unroll 4
    for (int t = 0; t < LC; ++t) {
        const float xv = xp[(size_t)t * DM];
        float acc = Dd * xv;
#pragma unroll
        for (int n = 0; n < NS; ++n) {
            h[n] = fmaf(a[n], h[n], bb[n] * xv);
            acc  = fmaf(h[n], cc[n], acc);
        }
        yp[(size_t)t * DM] = acc;
    }
}

// ---------------------------------------------------------------------------
extern "C" void kernel_launch(void* const* d_in, const int* in_sizes, int n_in,
                              void* d_out, int out_size, void* d_ws, size_t ws_size,
                              hipStream_t stream) {
    const float* x     = (const float*)d_in[0];
    const float* A     = (const float*)d_in[1];
    const float* Bm    = (const float*)d_in[2];
    const float* Cm    = (const float*)d_in[3];
    const float* Dv    = (const float*)d_in[4];
    const float* delta = (const float*)d_in[5];
    float* y = (float*)d_out;

    float* carry = (float*)d_ws;   // BSZ*NC*NS*DM*4 = 8.4 MiB scratch

    dim3 blk(DM);
    dim3 grd(BSZ * NC);                  // 512 blocks -> 2 waves/SIMD
    k_local<<<grd, blk, 0, stream>>>(x, A, Bm, delta, carry);
    k_final<<<grd, blk, 0, stream>>>(x, A, Bm, Cm, Dv, delta, carry, y);
}

// Round 9
// 28.585 us; speedup vs baseline: 1.7996x; 1.7996x over previous
//
#include <hip/hip_runtime.h>

#define BSZ  8
#define LSEQ 2048
#define DM   256
#define NS   16
#define NC   32          // chunks along L
#define LC   (LSEQ/NC)   // 64 timesteps per chunk
#define TILE_FLOATS (LC * DM)            // 16384 floats = 64 KB LDS tile
#define VEC_ROUNDS  (TILE_FLOATS / 4 / DM)  // 16 float4 loads per thread

// ---------------------------------------------------------------------------
// Pass 1: per-(b,chunk) local scan, h0=0; emit carry.
// x tile is a CONTIGUOUS 64 KB region -> stage via float4 (16 B/lane, 4 KB
// per wave-load) into LDS; compute reads LDS (2-way bank alias = free).
// Round-7/8 lessons: depth & occupancy aren't the levers; transaction
// granularity is the remaining hypothesis (G13).
// ---------------------------------------------------------------------------
__global__ void k_local(
        const float* __restrict__ x,
        const float* __restrict__ A,
        const float* __restrict__ Bm,
        const float* __restrict__ delta,
        float* __restrict__ carry) {
    __shared__ float lx[TILE_FLOATS];
    const int d     = threadIdx.x;
    const int chunk = blockIdx.x & (NC - 1);
    const int b     = blockIdx.x / NC;

    {   // vectorized stage: 16 rounds x 256 threads x 16 B = 64 KB
        const float4* __restrict__ src =
            (const float4*)(x + ((size_t)(b * LSEQ + chunk * LC)) * DM);
        float4* dst = (float4*)lx;
#pragma unroll
        for (int r = 0; r < VEC_ROUNDS; ++r)
            dst[r * DM + d] = src[r * DM + d];
    }

    // coefficient transcendentals overlap the staging latency
    const float dt = 1.0f / (1.0f + expf(-delta[d]));
    float a[NS], bb[NS];
#pragma unroll
    for (int n = 0; n < NS; ++n) {
        a[n]  = expf(dt * A[d * NS + n]);
        bb[n] = dt * Bm[d * NS + n];
    }
    __syncthreads();

    float h[NS];
#pragma unroll
    for (int n = 0; n < NS; ++n) h[n] = 0.0f;
#pragma unroll 4
    for (int t = 0; t < LC; ++t) {
        const float xv = lx[t * DM + d];
#pragma unroll
        for (int n = 0; n < NS; ++n) h[n] = fmaf(a[n], h[n], bb[n] * xv);
    }

    float* cp = carry + ((size_t)(b * NC + chunk) * NS) * DM + d;
#pragma unroll
    for (int n = 0; n < NS; ++n) cp[(size_t)n * DM] = h[n];
}

// ---------------------------------------------------------------------------
// Pass 2: per-(b,n,d) sequential prefix over the NC chunk carries, in place.
// Unchanged from the 29.2 us baseline (traffic is small + L3-resident).
// ---------------------------------------------------------------------------
__global__ void k_prefix(
        const float* __restrict__ A,
        const float* __restrict__ delta,
        float* __restrict__ carry) {
    const int tid = blockIdx.x * 256 + threadIdx.x;   // 0 .. BSZ*NS*DM-1
    const int d = tid & (DM - 1);
    const int n = (tid >> 8) & (NS - 1);
    const int b = tid >> 12;

    const float dt = 1.0f / (1.0f + expf(-delta[d]));
    const float aL = expf(dt * A[d * NS + n] * (float)LC);

    float run = 0.0f;
    float* cp = carry + (size_t)b * NC * NS * DM + (size_t)n * DM + d;
#pragma unroll
    for (int j = 0; j < NC; ++j) {
        const size_t off = (size_t)j * NS * DM;
        const float c = cp[off];
        cp[off] = run;                 // state entering chunk j
        run = fmaf(aL, run, c);        // state leaving chunk j
    }
}

// ---------------------------------------------------------------------------
// Pass 3: seeded replay. Stage x tile via float4 -> LDS; compute y IN PLACE
// into the same LDS tile (slot (t,d) touched only by thread d); store the
// tile back to y as contiguous float4.
// ---------------------------------------------------------------------------
__global__ void k_final(
        const float* __restrict__ x,
        const float* __restrict__ A,
        const float* __restrict__ Bm,
        const float* __restrict__ Cm,
        const float* __restrict__ Dv,
        const float* __restrict__ delta,
        const float* __restrict__ hin,
        float* __restrict__ y) {
    __shared__ float lt[TILE_FLOATS];
    const int d     = threadIdx.x;
    const int chunk = blockIdx.x & (NC - 1);
    const int b     = blockIdx.x / NC;

    const size_t tile_base = ((size_t)(b * LSEQ + chunk * LC)) * DM;
    {   // vectorized stage
        const float4* __restrict__ src = (const float4*)(x + tile_base);
        float4* dst = (float4*)lt;
#pragma unroll
        for (int r = 0; r < VEC_ROUNDS; ++r)
            dst[r * DM + d] = src[r * DM + d];
    }

    // coefficients + entry state overlap staging latency
    const float dt = 1.0f / (1.0f + expf(-delta[d]));
    float a[NS], bb[NS], cc[NS];
#pragma unroll
    for (int n = 0; n < NS; ++n) {
        a[n]  = expf(dt * A[d * NS + n]);
        bb[n] = dt * Bm[d * NS + n];
        cc[n] = Cm[d * NS + n];
    }
    const float Dd = Dv[d];

    float h[NS];
    const float* hp = hin + ((size_t)(b * NC + chunk) * NS) * DM + d;
#pragma unroll
    for (int n = 0; n < NS; ++n) h[n] = hp[(size_t)n * DM];

    __syncthreads();

#pragma unroll 4
    for (int t = 0; t < LC; ++t) {
        const float xv = lt[t * DM + d];
        float acc = Dd * xv;
#pragma unroll
        for (int n = 0; n < NS; ++n) {
            h[n] = fmaf(a[n], h[n], bb[n] * xv);
            acc  = fmaf(h[n], cc[n], acc);
        }
        lt[t * DM + d] = acc;          // in-place: only thread d touches (t,d)
    }
    __syncthreads();

    {   // vectorized store of the y tile
        float4* __restrict__ dst = (float4*)(y + tile_base);
        const float4* src = (const float4*)lt;
#pragma unroll
        for (int r = 0; r < VEC_ROUNDS; ++r)
            dst[r * DM + d] = src[r * DM + d];
    }
}

// ---------------------------------------------------------------------------
extern "C" void kernel_launch(void* const* d_in, const int* in_sizes, int n_in,
                              void* d_out, int out_size, void* d_ws, size_t ws_size,
                              hipStream_t stream) {
    const float* x     = (const float*)d_in[0];
    const float* A     = (const float*)d_in[1];
    const float* Bm    = (const float*)d_in[2];
    const float* Cm    = (const float*)d_in[3];
    const float* Dv    = (const float*)d_in[4];
    const float* delta = (const float*)d_in[5];
    float* y = (float*)d_out;

    float* carry = (float*)d_ws;   // BSZ*NC*NS*DM*4 = 4.2 MiB scratch

    dim3 blk(DM);
    dim3 grd1(BSZ * NC);                 // 256 blocks
    k_local<<<grd1, blk, 0, stream>>>(x, A, Bm, delta, carry);

    dim3 grd2((BSZ * NS * DM) / 256);    // 128 blocks
    k_prefix<<<grd2, dim3(256), 0, stream>>>(A, delta, carry);

    k_final<<<grd1, blk, 0, stream>>>(x, A, Bm, Cm, Dv, delta, carry, y);
}